// Round 2
// baseline (438.012 us; speedup 1.0000x reference)
//
#include <hip/hip_runtime.h>

// Harness-provided kernel symbol kept (not required to do work).
__global__ void GraphEncoder_20555713479231_kernel() {}

using hfrag8 = __attribute__((ext_vector_type(8))) _Float16;  // 8 f16 (4 VGPRs)
using facc4  = __attribute__((ext_vector_type(4))) float;     // 4 fp32 acc
using h2     = __attribute__((ext_vector_type(2))) _Float16;  // packed f16 pair

__device__ __forceinline__ unsigned short f2h_bits(float f) {
  union { _Float16 h; unsigned short u; } c;
  c.h = (_Float16)f;
  return c.u;
}
__device__ __forceinline__ unsigned packh(float a, float b) {
  return (unsigned)f2h_bits(a) | ((unsigned)f2h_bits(b) << 16);
}
__device__ __forceinline__ h2 u2h(unsigned u) {
  union { unsigned u; h2 h; } c;
  c.u = u;
  return c.h;
}
__device__ __forceinline__ unsigned h22u(h2 h) {
  union { h2 h; unsigned u; } c;
  c.h = h;
  return c.u;
}
__device__ __forceinline__ float h2f_lo(unsigned u) { return (float)u2h(u).x; }
__device__ __forceinline__ float h2f_hi(unsigned u) { return (float)u2h(u).y; }

#define LOG2E 1.4426950408889634f

// ---------------- CSR build ----------------
__global__ __launch_bounds__(256) void k_hist(const int* __restrict__ dst,
                                              int* __restrict__ deg, int e) {
  int i = blockIdx.x * blockDim.x + threadIdx.x;
  if (i < e) atomicAdd(&deg[dst[i]], 1);
}

// parallel scan pass 1: per-block exclusive scan of (deg[i]+1); block totals to bsum
__global__ __launch_bounds__(256) void k_scan1(const int* __restrict__ deg,
                                               int* __restrict__ off,
                                               int* __restrict__ bsum, int n) {
  __shared__ int wsum[4];
  int tid = threadIdx.x;
  int gid = blockIdx.x * 256 + tid;
  int lane = tid & 63, wid = tid >> 6;
  int v = (gid < n) ? (deg[gid] + 1) : 0;
  int x = v;
  #pragma unroll
  for (int d = 1; d < 64; d <<= 1) {
    int t = __shfl_up(x, d);
    if (lane >= d) x += t;
  }
  if (lane == 63) wsum[wid] = x;
  __syncthreads();
  int wpre = 0;
  for (int k = 0; k < wid; ++k) wpre += wsum[k];
  if (gid < n) off[gid] = wpre + x - v;
  if (tid == 0) {
    int t = 0;
    #pragma unroll
    for (int k = 0; k < 4; ++k) t += wsum[k];
    bsum[blockIdx.x] = t;
  }
}

// merged scan2+scan3: each block computes its own prefix of bsum (nb <= 256-ish,
// loop handles larger), applies it, inits self-loop slot + fill cursor, and
// block 0 writes off[n] and zero-pads csr tail (16 ints) for the padded
// 16-edge group reads in k_agg_t.
__global__ __launch_bounds__(256) void k_scan23(int* __restrict__ off,
                                                const int* __restrict__ bsum,
                                                int* __restrict__ pos,
                                                int* __restrict__ csr, int nb, int n) {
  __shared__ int sh[8];
  int tid = threadIdx.x, lane = tid & 63, wid = tid >> 6;
  int p = 0, t = 0;
  for (int k = tid; k < nb; k += 256) {
    int bv = bsum[k];
    t += bv;
    if (k < (int)blockIdx.x) p += bv;
  }
  #pragma unroll
  for (int d = 1; d < 64; d <<= 1) {
    p += __shfl_xor(p, d);
    t += __shfl_xor(t, d);
  }
  if (lane == 0) { sh[wid] = p; sh[4 + wid] = t; }
  __syncthreads();
  p = sh[0] + sh[1] + sh[2] + sh[3];
  t = sh[4] + sh[5] + sh[6] + sh[7];
  int gid = blockIdx.x * 256 + tid;
  if (gid < n) {
    int o = off[gid] + p;
    off[gid] = o;
    csr[o] = gid;  // self-loop occupies first slot
    pos[gid] = o + 1;
  }
  if (blockIdx.x == 0) {
    if (tid == 0) off[n] = t;
    if (tid < 16) csr[t + tid] = 0;  // pad: reads past end hit valid row 0
  }
}

__global__ __launch_bounds__(256) void k_fill(const int* __restrict__ src,
                                              const int* __restrict__ dst,
                                              int* __restrict__ pos,
                                              int* __restrict__ csr, int e) {
  int i = blockIdx.x * blockDim.x + threadIdx.x;
  if (i < e) {
    int d = dst[i];
    int p = atomicAdd(&pos[d], 1);
    csr[p] = src[i];
  }
}

// ---------------- pack weights (3 layers) + layer-0 tables + bit-packed types ------
// blocks 0..383: bp[layer][((t*16+ct)*64+lane)*8+j] =
//   W[k=t*32+(lane>>4)*8+j][c=ct*16+(lane&15)], c<128->Wl else Wr (f16)
// block 384: emb @ W0 tables -> tlb (f16 pairs), trf (f32)
// blocks 385..385+npkB: ptypes[i] packs types at 2 bits each (12.5 KB, L1-hot)
// remaining blocks: zero deg (replaces hipMemsetAsync dispatch)
__global__ __launch_bounds__(256)
void k_pack3(const float* __restrict__ wl1, const float* __restrict__ wr1,
             const float* __restrict__ wl2, const float* __restrict__ wr2,
             const float* __restrict__ wl3, const float* __restrict__ wr3,
             const float* __restrict__ emb,
             const float* __restrict__ wl0, const float* __restrict__ wr0,
             const int* __restrict__ types, int n,
             unsigned short* __restrict__ bp,
             unsigned* __restrict__ tlb, float* __restrict__ trf,
             unsigned* __restrict__ ptypes, int* __restrict__ deg, int npkB) {
  int b = blockIdx.x;
  if (b < 384) {
    int idx = b * 256 + threadIdx.x;  // 0..98303
    int layer = idx >> 15;
    int r = idx & 32767;
    int j = r & 7, lane = (r >> 3) & 63, ct = (r >> 9) & 15, t = r >> 13;
    int k = t * 32 + (lane >> 4) * 8 + j;
    int c = ct * 16 + (lane & 15);
    const float* wl = (layer == 0) ? wl1 : ((layer == 1) ? wl2 : wl3);
    const float* wr = (layer == 0) ? wr1 : ((layer == 1) ? wr2 : wr3);
    float v = (c < 128) ? wl[k * 128 + c] : wr[k * 128 + (c - 128)];
    bp[idx] = f2h_bits(v);
  } else if (b == 384) {
    int tid = threadIdx.x;
    if (tid >= 192) return;
    int row = tid >> 6, cp = tid & 63, c0 = cp * 2;
    float al0 = 0.f, al1 = 0.f, ar0 = 0.f, ar1 = 0.f;
    #pragma unroll
    for (int k = 0; k < 16; ++k) {
      float ev = emb[row * 16 + k];
      al0 += ev * wl0[k * 128 + c0];
      al1 += ev * wl0[k * 128 + c0 + 1];
      ar0 += ev * wr0[k * 128 + c0];
      ar1 += ev * wr0[k * 128 + c0 + 1];
    }
    tlb[row * 64 + cp] = packh(al0, al1);
    *(float2*)(trf + row * 128 + c0) = make_float2(ar0, ar1);
  } else if (b < 385 + npkB) {
    int i = (b - 385) * 256 + threadIdx.x;
    int npk = (n + 15) >> 4;
    if (i < npk) {
      unsigned pw = 0;
      #pragma unroll
      for (int j = 0; j < 16; ++j) {
        int u = i * 16 + j;
        int ty = (u < n) ? (types[u] & 3) : 3;
        pw |= ((unsigned)ty) << (2 * j);
      }
      ptypes[i] = pw;
    }
  } else {
    int i = (b - 385 - npkB) * 256 + threadIdx.x;
    if (i < n) deg[i] = 0;
  }
}

// ---------------- layer-0 aggregation via neighbor-type histogram ----------------
__global__ __launch_bounds__(256)
void k_agg0(const int* __restrict__ off, const int* __restrict__ csr,
            const unsigned* __restrict__ ptypes,
            const unsigned* __restrict__ tlb, const float* __restrict__ trf,
            const float* __restrict__ att, const float* __restrict__ bias,
            const float* __restrict__ lng, const float* __restrict__ lnb,
            unsigned* __restrict__ yout, int n) {
  int v = (blockIdx.x * blockDim.x + threadIdx.x) >> 6;
  int lane = threadIdx.x & 63;
  if (v >= n) return;
  v = __builtin_amdgcn_readfirstlane(v);
  int beg = off[v], end = off[v + 1];
  int c0 = 0, c1 = 0, c2 = 0;
  for (int base = beg; base < end; base += 64) {
    int e = base + lane;
    bool act = e < end;
    int u = act ? csr[e] : 0;
    unsigned pw = ptypes[u >> 4];
    int ty = act ? (int)((pw >> ((u & 15) * 2)) & 3) : 3;
    c0 += __popcll(__ballot(ty == 0));
    c1 += __popcll(__ballot(ty == 1));
    c2 += __popcll(__ballot(ty == 2));
  }
  float cnt[3] = {(float)c0, (float)c1, (float)c2};
  int f0 = lane * 2;
  unsigned pwv = ptypes[v >> 4];
  int tyv = (int)((pwv >> ((v & 15) * 2)) & 3);
  float2 xrv = *(const float2*)(trf + tyv * 128 + f0);
  float a0 = att[f0] * LOG2E, a1 = att[f0 + 1] * LOG2E;
  float s = 0.f, O0 = 0.f, O1 = 0.f;
  #pragma unroll
  for (int ty = 0; ty < 3; ++ty) {
    unsigned p = tlb[ty * 64 + lane];
    float x0 = h2f_lo(p), x1 = h2f_hi(p);
    float t0 = x0 + xrv.x; t0 = t0 > 0.f ? t0 : 0.2f * t0;
    float t1 = x1 + xrv.y; t1 = t1 > 0.f ? t1 : 0.2f * t1;
    float c = t0 * a0 + t1 * a1;
    c += __shfl_xor(c, 1);
    c += __shfl_xor(c, 2);
    c += __shfl_xor(c, 4);
    c += __shfl_xor(c, 8);
    float w = cnt[ty] * __builtin_amdgcn_exp2f(c);
    s += w;
    O0 = fmaf(w, x0, O0);
    O1 = fmaf(w, x1, O1);
  }
  float inv = 1.f / s;
  float o0 = O0 * inv + bias[f0];
  float o1 = O1 * inv + bias[f0 + 1];
  float sum = o0 + o1, sq = o0 * o0 + o1 * o1;
  #pragma unroll
  for (int d2 = 1; d2 < 64; d2 <<= 1) {
    sum += __shfl_xor(sum, d2);
    sq += __shfl_xor(sq, d2);
  }
  float mu = sum * (1.f / 128.f);
  float var = sq * (1.f / 128.f) - mu * mu;
  float rstd = rsqrtf(var + 1e-5f);
  float y0 = fmaxf((o0 - mu) * rstd * lng[f0] + lnb[f0], 0.f);
  float y1 = fmaxf((o1 - mu) * rstd * lng[f0 + 1] + lnb[f0 + 1], 0.f);
  yout[(size_t)v * 64 + lane] = packh(y0, y1);
}

// ---------------- GEMM (MFMA f16): x(Nx128 f16 packed) @ [Wl|Wr] -> xl, xr ----
__global__ __launch_bounds__(256)
void k_gemm(const unsigned* __restrict__ x, const unsigned short* __restrict__ bp,
            unsigned* __restrict__ xlo, unsigned* __restrict__ xro, int nstrips, int n) {
  int wave = (blockIdx.x * 256 + threadIdx.x) >> 6;
  int lane = threadIdx.x & 63;
  if (wave >= nstrips) return;
  int r0 = wave * 16;
  int row = r0 + (lane & 15);
  if (row >= n) row = n - 1;
  int quad = lane >> 4;
  const unsigned* ap = x + (size_t)row * 64;
  hfrag8 a[4];
  #pragma unroll
  for (int t = 0; t < 4; ++t) a[t] = *(const hfrag8*)(ap + t * 16 + quad * 4);
  unsigned short* xloS = (unsigned short*)xlo;
  unsigned short* xroS = (unsigned short*)xro;
  int rbase = r0 + quad * 4;
  #pragma unroll
  for (int ct = 0; ct < 16; ++ct) {
    facc4 acc = {0.f, 0.f, 0.f, 0.f};
    #pragma unroll
    for (int t = 0; t < 4; ++t) {
      hfrag8 b = *(const hfrag8*)(bp + (size_t)(((t * 16 + ct) * 64 + lane) * 8));
      acc = __builtin_amdgcn_mfma_f32_16x16x32_f16(a[t], b, acc, 0, 0, 0);
    }
    int col = (ct & 7) * 16 + (lane & 15);
    unsigned short* dstp = (ct < 8) ? xloS : xroS;
    #pragma unroll
    for (int i = 0; i < 4; ++i) {
      int r = rbase + i;
      if (r < n) dstp[(size_t)r * 128 + col] = f2h_bits(acc[i]);
    }
  }
}

// ---------------- fused aggregate + bias + residual + LN + ReLU (f16 packed) ----------
// one wave per dst node; lane owns features 2*lane, 2*lane+1.
// 16-edge groups: edge row indices come from uniform (scalar) csr reads
// (s_load_dwordx16), gathers are saddr-form (scalar base + lane*4).
// 8 independent packed-f16 shuffle trees per group -> tree latency amortized
// over 16 edges instead of 2 (the R1 critical path). One-group-ahead prefetch.
// att pre-scaled by log2e so softmax exp is a single v_exp_f32.
template <int WIDE>
__global__ __launch_bounds__(256)
void k_agg_t(const int* __restrict__ off, const int* __restrict__ csr,
             const unsigned* __restrict__ xl, const unsigned* __restrict__ xr,
             const float* __restrict__ att, const float* __restrict__ bias,
             const unsigned* __restrict__ xres,
             const float* __restrict__ lng, const float* __restrict__ lnb,
             unsigned* __restrict__ ybf, float* __restrict__ yf32, int n) {
  int v = (blockIdx.x * blockDim.x + threadIdx.x) >> 6;
  int lane = threadIdx.x & 63;
  if (v >= n) return;
  v = __builtin_amdgcn_readfirstlane(v);
  int f0 = lane * 2;
  h2 a2;
  a2.x = (_Float16)(att[f0] * LOG2E);
  a2.y = (_Float16)(att[f0 + 1] * LOG2E);
  h2 r2 = u2h(xr[(size_t)v * 64 + lane]);
  h2 k02 = {(_Float16)0.2f, (_Float16)0.2f};
  int beg = __builtin_amdgcn_readfirstlane(off[v]);
  int end = __builtin_amdgcn_readfirstlane(off[v + 1]);
  int m = end - beg;
  const int* cw = csr + beg;  // uniform base -> scalar loads
  float sv[4] = {0.f, 0.f, 0.f, 0.f};
  h2 Ov[4];
  Ov[0] = h2{(_Float16)0.f, (_Float16)0.f};
  Ov[1] = Ov[0]; Ov[2] = Ov[0]; Ov[3] = Ov[0];

  unsigned A[16], B[16];

  auto load16 = [&](unsigned* buf, int g) {
    #pragma unroll
    for (int i = 0; i < 16; ++i) {
      int r = cw[g * 16 + i];  // uniform -> SGPR
      buf[i] = xl[(((unsigned)r) << 6) + (unsigned)lane];  // saddr + lane*4
    }
  };

  auto compute = [&](const unsigned* buf, int mloc) {
    h2 cp[8];
    #pragma unroll
    for (int j = 0; j < 8; ++j) {
      h2 xa = u2h(buf[2 * j]), xb = u2h(buf[2 * j + 1]);
      h2 ta = xa + r2, tb = xb + r2;
      h2 la = __builtin_elementwise_max(ta, ta * k02);  // pk leaky relu
      h2 lb = __builtin_elementwise_max(tb, tb * k02);
      h2 da = la * a2, db = lb * a2;
      h2 c;
      c.x = da.x + da.y;  // edge 2j partial logit (log2 units)
      c.y = db.x + db.y;  // edge 2j+1
      cp[j] = c;
    }
    // 8 interleaved packed reduction trees (level latency shared by 16 edges)
    #pragma unroll
    for (int lvl = 1; lvl <= (WIDE ? 32 : 8); lvl <<= 1) {
      unsigned t[8];
      #pragma unroll
      for (int j = 0; j < 8; ++j) t[j] = (unsigned)__shfl_xor((int)h22u(cp[j]), lvl);
      #pragma unroll
      for (int j = 0; j < 8; ++j) cp[j] = cp[j] + u2h(t[j]);
    }
    float lgs[16];
    #pragma unroll
    for (int j = 0; j < 8; ++j) {
      lgs[2 * j] = (float)cp[j].x;
      lgs[2 * j + 1] = (float)cp[j].y;
    }
    if (mloc < 16) {  // tail group only: mask invalid slots
      #pragma unroll
      for (int i = 0; i < 16; ++i)
        if (i >= mloc) lgs[i] = -200.f;  // exp2 -> 0
    }
    #pragma unroll
    for (int i = 0; i < 16; ++i) {
      float w = __builtin_amdgcn_exp2f(lgs[i]);
      sv[i & 3] += w;
      _Float16 wh = (_Float16)w;
      h2 w2 = {wh, wh};
      Ov[i & 3] = w2 * u2h(buf[i]) + Ov[i & 3];  // v_pk_fma_f16
    }
  };

  int ng = (m + 15) >> 4;
  load16(A, 0);
  if (ng > 1) load16(B, 1);
  int g = 0;
  for (;;) {
    {
      int rem = m - g * 16;
      compute(A, rem >= 16 ? 16 : rem);
    }
    ++g;
    if (g >= ng) break;
    if (g + 1 < ng) load16(A, g + 1);
    {
      int rem = m - g * 16;
      compute(B, rem >= 16 ? 16 : rem);
    }
    ++g;
    if (g >= ng) break;
    if (g + 1 < ng) load16(B, g + 1);
  }

  float s = (sv[0] + sv[1]) + (sv[2] + sv[3]);
  float Ox = ((float)Ov[0].x + (float)Ov[1].x) + ((float)Ov[2].x + (float)Ov[3].x);
  float Oy = ((float)Ov[0].y + (float)Ov[1].y) + ((float)Ov[2].y + (float)Ov[3].y);
  float inv = 1.f / s;
  float o0 = Ox * inv + bias[f0];
  float o1 = Oy * inv + bias[f0 + 1];
  if (xres) {
    unsigned rs = xres[(size_t)v * 64 + lane];
    o0 += h2f_lo(rs);
    o1 += h2f_hi(rs);
  }
  float sum = o0 + o1, sq = o0 * o0 + o1 * o1;
  #pragma unroll
  for (int d2 = 1; d2 < 64; d2 <<= 1) {
    sum += __shfl_xor(sum, d2);
    sq += __shfl_xor(sq, d2);
  }
  float mu = sum * (1.f / 128.f);
  float var = sq * (1.f / 128.f) - mu * mu;
  float rstd = rsqrtf(var + 1e-5f);
  float y0 = fmaxf((o0 - mu) * rstd * lng[f0] + lnb[f0], 0.f);
  float y1 = fmaxf((o1 - mu) * rstd * lng[f0 + 1] + lnb[f0 + 1], 0.f);
  if (yf32) {
    *(float2*)(yf32 + (size_t)v * 128 + f0) = make_float2(y0, y1);
  } else {
    ybf[(size_t)v * 64 + lane] = packh(y0, y1);
  }
}

// ---------------- launch ----------------
extern "C" void kernel_launch(void* const* d_in, const int* in_sizes, int n_in,
                              void* d_out, int out_size, void* d_ws, size_t ws_size,
                              hipStream_t stream) {
  (void)n_in; (void)out_size; (void)ws_size;
  const int* node_types = (const int*)d_in[0];
  const int* edge_index = (const int*)d_in[1];
  const float* emb = (const float*)d_in[2];
  const float* Wl0 = (const float*)d_in[3];
  const float* Wr0 = (const float*)d_in[4];
  const float* att0 = (const float*)d_in[5];
  const float* b0 = (const float*)d_in[6];
  const float* Wl1 = (const float*)d_in[7];
  const float* Wr1 = (const float*)d_in[8];
  const float* att1 = (const float*)d_in[9];
  const float* b1 = (const float*)d_in[10];
  const float* Wl2 = (const float*)d_in[11];
  const float* Wr2 = (const float*)d_in[12];
  const float* att2 = (const float*)d_in[13];
  const float* b2 = (const float*)d_in[14];
  const float* Wl3 = (const float*)d_in[15];
  const float* Wr3 = (const float*)d_in[16];
  const float* att3 = (const float*)d_in[17];
  const float* b3 = (const float*)d_in[18];
  const float* lng = (const float*)d_in[19];
  const float* lnb = (const float*)d_in[20];

  int n = in_sizes[0];
  int e = in_sizes[1] / 2;
  const int* srcp = edge_index;
  const int* dstp = edge_index + e;
  int nblocks = (n + 255) / 256;

  // workspace carve (256-byte aligned chunks)
  char* wsp = (char*)d_ws;
  size_t ofs = 0;
  int* deg = (int*)(wsp + ofs); ofs += (((size_t)n * 4) + 255) & ~(size_t)255;
  int* off = (int*)(wsp + ofs); ofs += (((size_t)(n + 1) * 4) + 255) & ~(size_t)255;
  int* csr = (int*)(wsp + ofs); ofs += (((size_t)(e + n + 64) * 4) + 255) & ~(size_t)255;
  int* bsum = (int*)(wsp + ofs); ofs += (((size_t)nblocks * 4) + 255) & ~(size_t)255;
  unsigned* xlb = (unsigned*)(wsp + ofs); ofs += (((size_t)n * 64 * 4) + 255) & ~(size_t)255;
  unsigned* xrb = (unsigned*)(wsp + ofs); ofs += (((size_t)n * 64 * 4) + 255) & ~(size_t)255;
  unsigned* xcur = (unsigned*)(wsp + ofs); ofs += (((size_t)n * 64 * 4) + 255) & ~(size_t)255;
  unsigned short* bp = (unsigned short*)(wsp + ofs); ofs += 3 * 65536;
  unsigned* tlb = (unsigned*)(wsp + ofs); ofs += 1024;
  float* trf = (float*)(wsp + ofs); ofs += 2048;
  unsigned* ptypes = (unsigned*)(wsp + ofs); ofs += ((((size_t)(n + 15) / 16) * 4) + 255) & ~(size_t)255;
  int* pos = deg;  // deg dead after scan; reuse as fill cursor

  // pack (also zeroes deg -> replaces memset dispatch), then CSR build
  int npk = (n + 15) / 16;
  int npkB = (npk + 255) / 256;
  int packGrid = 385 + npkB + nblocks;
  k_pack3<<<packGrid, 256, 0, stream>>>(Wl1, Wr1, Wl2, Wr2, Wl3, Wr3,
                                        emb, Wl0, Wr0, node_types, n,
                                        bp, tlb, trf, ptypes, deg, npkB);
  k_hist<<<(e + 255) / 256, 256, 0, stream>>>(dstp, deg, e);
  k_scan1<<<nblocks, 256, 0, stream>>>(deg, off, bsum, n);
  k_scan23<<<nblocks, 256, 0, stream>>>(off, bsum, pos, csr, nblocks, n);
  k_fill<<<(e + 255) / 256, 256, 0, stream>>>(srcp, dstp, pos, csr, e);

  int aggBlocks = (n * 64 + 255) / 256;  // one wave per node

  // layer 0: type-table aggregation (ballot histogram from packed types)
  k_agg0<<<aggBlocks, 256, 0, stream>>>(off, csr, ptypes, tlb, trf,
                                        att0, b0, lng, lnb, xcur, n);

  int nstrips = (n + 15) / 16;
  int gemmBlocks = (nstrips + 3) / 4;

  // layer 1
  k_gemm<<<gemmBlocks, 256, 0, stream>>>(xcur, bp, xlb, xrb, nstrips, n);
  k_agg_t<0><<<aggBlocks, 256, 0, stream>>>(off, csr, xlb, xrb, att1, b1, xcur,
                                            lng + 128, lnb + 128, xcur, (float*)0, n);
  // layer 2
  k_gemm<<<gemmBlocks, 256, 0, stream>>>(xcur, bp + 32768, xlb, xrb, nstrips, n);
  k_agg_t<0><<<aggBlocks, 256, 0, stream>>>(off, csr, xlb, xrb, att2, b2, xcur,
                                            lng + 256, lnb + 256, xcur, (float*)0, n);
  // layer 3 (single head, wide reduce; f32 output to d_out)
  k_gemm<<<gemmBlocks, 256, 0, stream>>>(xcur, bp + 65536, xlb, xrb, nstrips, n);
  k_agg_t<1><<<aggBlocks, 256, 0, stream>>>(off, csr, xlb, xrb, att3, b3, xcur,
                                            lng + 384, lnb + 384, (unsigned*)0, (float*)d_out, n);
}

// Round 3
// 421.125 us; speedup vs baseline: 1.0401x; 1.0401x over previous
//
#include <hip/hip_runtime.h>

// Harness-provided kernel symbol kept (not required to do work).
__global__ void GraphEncoder_20555713479231_kernel() {}

using hfrag8 = __attribute__((ext_vector_type(8))) _Float16;  // 8 f16 (4 VGPRs)
using facc4  = __attribute__((ext_vector_type(4))) float;     // 4 fp32 acc
using h2     = __attribute__((ext_vector_type(2))) _Float16;  // packed f16 pair

__device__ __forceinline__ unsigned short f2h_bits(float f) {
  union { _Float16 h; unsigned short u; } c;
  c.h = (_Float16)f;
  return c.u;
}
__device__ __forceinline__ unsigned packh(float a, float b) {
  return (unsigned)f2h_bits(a) | ((unsigned)f2h_bits(b) << 16);
}
__device__ __forceinline__ h2 u2h(unsigned u) {
  union { unsigned u; h2 h; } c;
  c.u = u;
  return c.h;
}
__device__ __forceinline__ unsigned h22u(h2 h) {
  union { h2 h; unsigned u; } c;
  c.h = h;
  return c.u;
}
__device__ __forceinline__ float h2f_lo(unsigned u) { return (float)u2h(u).x; }
__device__ __forceinline__ float h2f_hi(unsigned u) { return (float)u2h(u).y; }

#define LOG2E 1.4426950408889634f

// ---------------- CSR build ----------------
// deg histogram + packed neighbor-type counts (c0 in lo16, c1 in hi16).
__global__ __launch_bounds__(256) void k_hist(const int* __restrict__ src,
                                              const int* __restrict__ dst,
                                              const int* __restrict__ types,
                                              int* __restrict__ deg,
                                              unsigned* __restrict__ h01, int e) {
  int i = blockIdx.x * blockDim.x + threadIdx.x;
  if (i >= e) return;
  int d = dst[i];
  atomicAdd(&deg[d], 1);
  int ty = types[src[i]] & 3;
  if (ty < 2) atomicAdd(&h01[d], ty == 0 ? 1u : 65536u);
}

// parallel scan pass 1: per-block exclusive scan of (deg[i]+1); block totals to bsum
__global__ __launch_bounds__(256) void k_scan1(const int* __restrict__ deg,
                                               int* __restrict__ off,
                                               int* __restrict__ bsum, int n) {
  __shared__ int wsum[4];
  int tid = threadIdx.x;
  int gid = blockIdx.x * 256 + tid;
  int lane = tid & 63, wid = tid >> 6;
  int v = (gid < n) ? (deg[gid] + 1) : 0;
  int x = v;
  #pragma unroll
  for (int d = 1; d < 64; d <<= 1) {
    int t = __shfl_up(x, d);
    if (lane >= d) x += t;
  }
  if (lane == 63) wsum[wid] = x;
  __syncthreads();
  int wpre = 0;
  for (int k = 0; k < wid; ++k) wpre += wsum[k];
  if (gid < n) off[gid] = wpre + x - v;
  if (tid == 0) {
    int t = 0;
    #pragma unroll
    for (int k = 0; k < 4; ++k) t += wsum[k];
    bsum[blockIdx.x] = t;
  }
}

// merged scan2+scan3: each block computes its own prefix of bsum, applies it,
// inits self-loop slot + fill cursor; block 0 writes off[n] + csr tail pad.
__global__ __launch_bounds__(256) void k_scan23(int* __restrict__ off,
                                                const int* __restrict__ bsum,
                                                int* __restrict__ pos,
                                                int* __restrict__ csr, int nb, int n) {
  __shared__ int sh[8];
  int tid = threadIdx.x, lane = tid & 63, wid = tid >> 6;
  int p = 0, t = 0;
  for (int k = tid; k < nb; k += 256) {
    int bv = bsum[k];
    t += bv;
    if (k < (int)blockIdx.x) p += bv;
  }
  #pragma unroll
  for (int d = 1; d < 64; d <<= 1) {
    p += __shfl_xor(p, d);
    t += __shfl_xor(t, d);
  }
  if (lane == 0) { sh[wid] = p; sh[4 + wid] = t; }
  __syncthreads();
  p = sh[0] + sh[1] + sh[2] + sh[3];
  t = sh[4] + sh[5] + sh[6] + sh[7];
  int gid = blockIdx.x * 256 + tid;
  if (gid < n) {
    int o = off[gid] + p;
    off[gid] = o;
    csr[o] = gid;  // self-loop occupies first slot
    pos[gid] = o + 1;
  }
  if (blockIdx.x == 0) {
    if (tid == 0) off[n] = t;
    if (tid < 16) csr[t + tid] = 0;  // pad: safe reads past end
  }
}

__global__ __launch_bounds__(256) void k_fill(const int* __restrict__ src,
                                              const int* __restrict__ dst,
                                              int* __restrict__ pos,
                                              int* __restrict__ csr, int e) {
  int i = blockIdx.x * blockDim.x + threadIdx.x;
  if (i < e) {
    int d = dst[i];
    int p = atomicAdd(&pos[d], 1);
    csr[p] = src[i];
  }
}

// ---------------- pack weights (3 layers) + layer-0 tables + zero deg/h01 ------
// blocks 0..383: bp[layer][((t*16+ct)*64+lane)*8+j] =
//   W[k=t*32+(lane>>4)*8+j][c=ct*16+(lane&15)], c<128->Wl else Wr (f16)
// block 384: emb @ W0 -> tlb (f16 pairs) + w0tab (36 exp2-logits, f32)
// remaining blocks: zero deg + h01 (replaces memset dispatches)
__global__ __launch_bounds__(256)
void k_pack3(const float* __restrict__ wl1, const float* __restrict__ wr1,
             const float* __restrict__ wl2, const float* __restrict__ wr2,
             const float* __restrict__ wl3, const float* __restrict__ wr3,
             const float* __restrict__ emb,
             const float* __restrict__ wl0, const float* __restrict__ wr0,
             const float* __restrict__ att0, int n,
             unsigned short* __restrict__ bp,
             unsigned* __restrict__ tlb, float* __restrict__ w0tab,
             int* __restrict__ deg, unsigned* __restrict__ h01) {
  int b = blockIdx.x;
  if (b < 384) {
    int idx = b * 256 + threadIdx.x;  // 0..98303
    int layer = idx >> 15;
    int r = idx & 32767;
    int j = r & 7, lane = (r >> 3) & 63, ct = (r >> 9) & 15, t = r >> 13;
    int k = t * 32 + (lane >> 4) * 8 + j;
    int c = ct * 16 + (lane & 15);
    const float* wl = (layer == 0) ? wl1 : ((layer == 1) ? wl2 : wl3);
    const float* wr = (layer == 0) ? wr1 : ((layer == 1) ? wr2 : wr3);
    float v = (c < 128) ? wl[k * 128 + c] : wr[k * 128 + (c - 128)];
    bp[idx] = f2h_bits(v);
  } else if (b == 384) {
    __shared__ float stl[384], str[384];
    int tid = threadIdx.x;
    if (tid < 192) {
      int row = tid >> 6, cp = tid & 63, c0 = cp * 2;
      float al0 = 0.f, al1 = 0.f, ar0 = 0.f, ar1 = 0.f;
      #pragma unroll
      for (int k = 0; k < 16; ++k) {
        float ev = emb[row * 16 + k];
        al0 += ev * wl0[k * 128 + c0];
        al1 += ev * wl0[k * 128 + c0 + 1];
        ar0 += ev * wr0[k * 128 + c0];
        ar1 += ev * wr0[k * 128 + c0 + 1];
      }
      tlb[row * 64 + cp] = packh(al0, al1);
      stl[row * 128 + c0] = al0; stl[row * 128 + c0 + 1] = al1;
      str[row * 128 + c0] = ar0; str[row * 128 + c0 + 1] = ar1;
    }
    __syncthreads();
    if (tid < 192) {
      int tyv = tid >> 6, lane = tid & 63, f0 = lane * 2;
      float xr0 = str[tyv * 128 + f0], xr1 = str[tyv * 128 + f0 + 1];
      float a0 = att0[f0] * LOG2E, a1 = att0[f0 + 1] * LOG2E;
      #pragma unroll
      for (int ty = 0; ty < 3; ++ty) {
        float x0 = stl[ty * 128 + f0], x1 = stl[ty * 128 + f0 + 1];
        float t0 = x0 + xr0; t0 = t0 > 0.f ? t0 : 0.2f * t0;
        float t1 = x1 + xr1; t1 = t1 > 0.f ? t1 : 0.2f * t1;
        float c = t0 * a0 + t1 * a1;
        c += __shfl_xor(c, 1);
        c += __shfl_xor(c, 2);
        c += __shfl_xor(c, 4);
        c += __shfl_xor(c, 8);
        if ((lane & 15) == 0)
          w0tab[(tyv * 3 + ty) * 4 + (lane >> 4)] = __builtin_amdgcn_exp2f(c);
      }
    }
  } else {
    int i = (b - 385) * 256 + threadIdx.x;
    if (i < n) { deg[i] = 0; h01[i] = 0u; }
  }
}

// ---------------- layer-0: closed-form from neighbor-type histogram ----------------
// out depends only on (type(v), c0, c1, c2); attention weights from 36-entry table.
__global__ __launch_bounds__(256)
void k_agg0h(const int* __restrict__ off, const unsigned* __restrict__ h01,
             const int* __restrict__ types,
             const unsigned* __restrict__ tlb, const float* __restrict__ w0tab,
             const float* __restrict__ bias,
             const float* __restrict__ lng, const float* __restrict__ lnb,
             unsigned* __restrict__ yout, int n) {
  int v = (blockIdx.x * blockDim.x + threadIdx.x) >> 6;
  int lane = threadIdx.x & 63;
  if (v >= n) return;
  v = __builtin_amdgcn_readfirstlane(v);
  int beg = off[v], end = off[v + 1];
  int m = end - beg;  // includes self-loop
  unsigned hc = h01[v];
  int tyv = types[v] & 3;
  float cnt[3];
  int c0 = (int)(hc & 0xffffu), c1 = (int)(hc >> 16);
  cnt[0] = (float)c0;
  cnt[1] = (float)c1;
  cnt[2] = (float)((m - 1) - c0 - c1);
  cnt[tyv] += 1.f;  // self-loop
  int head = lane >> 4;
  int f0 = lane * 2;
  float s = 0.f, O0 = 0.f, O1 = 0.f;
  #pragma unroll
  for (int ty = 0; ty < 3; ++ty) {
    float w = cnt[ty] * w0tab[(tyv * 3 + ty) * 4 + head];
    unsigned p = tlb[ty * 64 + lane];
    s += w;
    O0 = fmaf(w, h2f_lo(p), O0);
    O1 = fmaf(w, h2f_hi(p), O1);
  }
  float inv = 1.f / s;
  float o0 = O0 * inv + bias[f0];
  float o1 = O1 * inv + bias[f0 + 1];
  float sum = o0 + o1, sq = o0 * o0 + o1 * o1;
  #pragma unroll
  for (int d2 = 1; d2 < 64; d2 <<= 1) {
    sum += __shfl_xor(sum, d2);
    sq += __shfl_xor(sq, d2);
  }
  float mu = sum * (1.f / 128.f);
  float var = sq * (1.f / 128.f) - mu * mu;
  float rstd = rsqrtf(var + 1e-5f);
  float y0 = fmaxf((o0 - mu) * rstd * lng[f0] + lnb[f0], 0.f);
  float y1 = fmaxf((o1 - mu) * rstd * lng[f0 + 1] + lnb[f0 + 1], 0.f);
  yout[(size_t)v * 64 + lane] = packh(y0, y1);
}

// ---------------- GEMM (MFMA f16): x(Nx128 f16 packed) @ [Wl|Wr] -> xl, xr ----
__global__ __launch_bounds__(256)
void k_gemm(const unsigned* __restrict__ x, const unsigned short* __restrict__ bp,
            unsigned* __restrict__ xlo, unsigned* __restrict__ xro, int nstrips, int n) {
  int wave = (blockIdx.x * 256 + threadIdx.x) >> 6;
  int lane = threadIdx.x & 63;
  if (wave >= nstrips) return;
  int r0 = wave * 16;
  int row = r0 + (lane & 15);
  if (row >= n) row = n - 1;
  int quad = lane >> 4;
  const unsigned* ap = x + (size_t)row * 64;
  hfrag8 a[4];
  #pragma unroll
  for (int t = 0; t < 4; ++t) a[t] = *(const hfrag8*)(ap + t * 16 + quad * 4);
  unsigned short* xloS = (unsigned short*)xlo;
  unsigned short* xroS = (unsigned short*)xro;
  int rbase = r0 + quad * 4;
  #pragma unroll
  for (int ct = 0; ct < 16; ++ct) {
    facc4 acc = {0.f, 0.f, 0.f, 0.f};
    #pragma unroll
    for (int t = 0; t < 4; ++t) {
      hfrag8 b = *(const hfrag8*)(bp + (size_t)(((t * 16 + ct) * 64 + lane) * 8));
      acc = __builtin_amdgcn_mfma_f32_16x16x32_f16(a[t], b, acc, 0, 0, 0);
    }
    int col = (ct & 7) * 16 + (lane & 15);
    unsigned short* dstp = (ct < 8) ? xloS : xroS;
    #pragma unroll
    for (int i = 0; i < 4; ++i) {
      int r = rbase + i;
      if (r < n) dstp[(size_t)r * 128 + col] = f2h_bits(acc[i]);
    }
  }
}

// ---------------- fused aggregate + bias + residual + LN + ReLU (f16 packed) ----------
// one wave per dst node; lane owns features 2*lane, 2*lane+1 (R0 structure, best
// measured). att pre-scaled by log2e -> single v_exp2 per edge.
__global__ __launch_bounds__(256)
void k_agg(const int* __restrict__ off, const int* __restrict__ csr,
           const unsigned* __restrict__ xl, const unsigned* __restrict__ xr,
           const float* __restrict__ att, const float* __restrict__ bias,
           const unsigned* __restrict__ xres,
           const float* __restrict__ lng, const float* __restrict__ lnb,
           unsigned* __restrict__ ybf, float* __restrict__ yf32, int n, int wide) {
  int v = (blockIdx.x * blockDim.x + threadIdx.x) >> 6;
  int lane = threadIdx.x & 63;
  if (v >= n) return;
  v = __builtin_amdgcn_readfirstlane(v);
  int f0 = lane * 2;
  h2 a2;
  a2.x = (_Float16)(att[f0] * LOG2E);
  a2.y = (_Float16)(att[f0 + 1] * LOG2E);
  h2 r2 = u2h(xr[(size_t)v * 64 + lane]);
  h2 k02 = {(_Float16)0.2f, (_Float16)0.2f};
  int beg = off[v], end = off[v + 1];
  int last = end - 1;
  const unsigned* xlp = xl + lane;  // row r at xlp[r*64]
  int iA = csr[beg];
  int iB = csr[min(beg + 1, last)];
  int iC = csr[min(beg + 2, last)];
  int iD = csr[min(beg + 3, last)];
  unsigned pA = xlp[(size_t)iA * 64];
  unsigned pB = xlp[(size_t)iB * 64];
  unsigned pC = xlp[(size_t)iC * 64];
  unsigned pD = xlp[(size_t)iD * 64];
  float sa = 0.f, sb = 0.f;
  h2 Oa = {(_Float16)0.f, (_Float16)0.f};
  h2 Ob = {(_Float16)0.f, (_Float16)0.f};
  for (int e = beg; e < end; e += 2) {
    int i4 = csr[min(e + 4, last)];
    int i5 = csr[min(e + 5, last)];
    unsigned p4 = xlp[(size_t)i4 * 64];
    unsigned p5 = xlp[(size_t)i5 * 64];
    h2 xa = u2h(pA), xb = u2h(pB);
    h2 ta = xa + r2;
    h2 tb = xb + r2;
    h2 la = __builtin_elementwise_max(ta, ta * k02);  // pk leaky relu
    h2 lb = __builtin_elementwise_max(tb, tb * k02);
    h2 da = la * a2;
    h2 db = lb * a2;
    h2 cp;
    cp.x = da.x + da.y;  // edge A partial logit (log2 units)
    cp.y = db.x + db.y;  // edge B partial logit
    unsigned cu = h22u(cp);
    cu = h22u(u2h(cu) + u2h((unsigned)__shfl_xor((int)cu, 1)));
    cu = h22u(u2h(cu) + u2h((unsigned)__shfl_xor((int)cu, 2)));
    cu = h22u(u2h(cu) + u2h((unsigned)__shfl_xor((int)cu, 4)));
    cu = h22u(u2h(cu) + u2h((unsigned)__shfl_xor((int)cu, 8)));
    if (wide) {
      cu = h22u(u2h(cu) + u2h((unsigned)__shfl_xor((int)cu, 16)));
      cu = h22u(u2h(cu) + u2h((unsigned)__shfl_xor((int)cu, 32)));
    }
    h2 cf = u2h(cu);
    float wa = __builtin_amdgcn_exp2f((float)cf.x);
    float wb = (e + 1 < end) ? __builtin_amdgcn_exp2f((float)cf.y) : 0.f;
    sa += wa;
    sb += wb;
    _Float16 wah = (_Float16)wa;
    _Float16 wbh = (_Float16)wb;
    h2 wa2 = {wah, wah};
    h2 wb2 = {wbh, wbh};
    Oa = wa2 * xa + Oa;  // v_pk_fma_f16
    Ob = wb2 * xb + Ob;
    pA = pC; pB = pD; pC = p4; pD = p5;
  }
  float s = sa + sb;
  float O0 = (float)Oa.x + (float)Ob.x;
  float O1 = (float)Oa.y + (float)Ob.y;
  float inv = 1.f / s;
  float o0 = O0 * inv + bias[f0];
  float o1 = O1 * inv + bias[f0 + 1];
  if (xres) {
    unsigned rs = xres[(size_t)v * 64 + lane];
    o0 += h2f_lo(rs);
    o1 += h2f_hi(rs);
  }
  float sum = o0 + o1, sq = o0 * o0 + o1 * o1;
  #pragma unroll
  for (int d2 = 1; d2 < 64; d2 <<= 1) {
    sum += __shfl_xor(sum, d2);
    sq += __shfl_xor(sq, d2);
  }
  float mu = sum * (1.f / 128.f);
  float var = sq * (1.f / 128.f) - mu * mu;
  float rstd = rsqrtf(var + 1e-5f);
  float y0 = fmaxf((o0 - mu) * rstd * lng[f0] + lnb[f0], 0.f);
  float y1 = fmaxf((o1 - mu) * rstd * lng[f0 + 1] + lnb[f0 + 1], 0.f);
  if (yf32) {
    *(float2*)(yf32 + (size_t)v * 128 + f0) = make_float2(y0, y1);
  } else {
    ybf[(size_t)v * 64 + lane] = packh(y0, y1);
  }
}

// ---------------- launch ----------------
extern "C" void kernel_launch(void* const* d_in, const int* in_sizes, int n_in,
                              void* d_out, int out_size, void* d_ws, size_t ws_size,
                              hipStream_t stream) {
  (void)n_in; (void)out_size; (void)ws_size;
  const int* node_types = (const int*)d_in[0];
  const int* edge_index = (const int*)d_in[1];
  const float* emb = (const float*)d_in[2];
  const float* Wl0 = (const float*)d_in[3];
  const float* Wr0 = (const float*)d_in[4];
  const float* att0 = (const float*)d_in[5];
  const float* b0 = (const float*)d_in[6];
  const float* Wl1 = (const float*)d_in[7];
  const float* Wr1 = (const float*)d_in[8];
  const float* att1 = (const float*)d_in[9];
  const float* b1 = (const float*)d_in[10];
  const float* Wl2 = (const float*)d_in[11];
  const float* Wr2 = (const float*)d_in[12];
  const float* att2 = (const float*)d_in[13];
  const float* b2 = (const float*)d_in[14];
  const float* Wl3 = (const float*)d_in[15];
  const float* Wr3 = (const float*)d_in[16];
  const float* att3 = (const float*)d_in[17];
  const float* b3 = (const float*)d_in[18];
  const float* lng = (const float*)d_in[19];
  const float* lnb = (const float*)d_in[20];

  int n = in_sizes[0];
  int e = in_sizes[1] / 2;
  const int* srcp = edge_index;
  const int* dstp = edge_index + e;
  int nblocks = (n + 255) / 256;

  // workspace carve (256-byte aligned chunks)
  char* wsp = (char*)d_ws;
  size_t ofs = 0;
  int* deg = (int*)(wsp + ofs); ofs += (((size_t)n * 4) + 255) & ~(size_t)255;
  int* off = (int*)(wsp + ofs); ofs += (((size_t)(n + 1) * 4) + 255) & ~(size_t)255;
  int* csr = (int*)(wsp + ofs); ofs += (((size_t)(e + n + 64) * 4) + 255) & ~(size_t)255;
  int* bsum = (int*)(wsp + ofs); ofs += (((size_t)nblocks * 4) + 255) & ~(size_t)255;
  unsigned* h01 = (unsigned*)(wsp + ofs); ofs += (((size_t)n * 4) + 255) & ~(size_t)255;
  unsigned* xlb = (unsigned*)(wsp + ofs); ofs += (((size_t)n * 64 * 4) + 255) & ~(size_t)255;
  unsigned* xrb = (unsigned*)(wsp + ofs); ofs += (((size_t)n * 64 * 4) + 255) & ~(size_t)255;
  unsigned* xcur = (unsigned*)(wsp + ofs); ofs += (((size_t)n * 64 * 4) + 255) & ~(size_t)255;
  unsigned short* bp = (unsigned short*)(wsp + ofs); ofs += 3 * 65536;
  unsigned* tlb = (unsigned*)(wsp + ofs); ofs += 1024;
  float* w0tab = (float*)(wsp + ofs); ofs += 256;
  int* pos = deg;  // deg dead after scan; reuse as fill cursor

  // pack (also zeroes deg+h01 -> replaces memset dispatch), then CSR build
  int packGrid = 385 + nblocks;
  k_pack3<<<packGrid, 256, 0, stream>>>(Wl1, Wr1, Wl2, Wr2, Wl3, Wr3,
                                        emb, Wl0, Wr0, att0, n,
                                        bp, tlb, w0tab, deg, h01);
  k_hist<<<(e + 255) / 256, 256, 0, stream>>>(srcp, dstp, node_types, deg, h01, e);
  k_scan1<<<nblocks, 256, 0, stream>>>(deg, off, bsum, n);
  k_scan23<<<nblocks, 256, 0, stream>>>(off, bsum, pos, csr, nblocks, n);
  k_fill<<<(e + 255) / 256, 256, 0, stream>>>(srcp, dstp, pos, csr, e);

  int aggBlocks = (n * 64 + 255) / 256;  // one wave per node

  // layer 0: closed-form histogram aggregation (no edge traversal)
  k_agg0h<<<aggBlocks, 256, 0, stream>>>(off, h01, node_types, tlb, w0tab,
                                         b0, lng, lnb, xcur, n);

  int nstrips = (n + 15) / 16;
  int gemmBlocks = (nstrips + 3) / 4;

  // layer 1
  k_gemm<<<gemmBlocks, 256, 0, stream>>>(xcur, bp, xlb, xrb, nstrips, n);
  k_agg<<<aggBlocks, 256, 0, stream>>>(off, csr, xlb, xrb, att1, b1, xcur,
                                       lng + 128, lnb + 128, xcur, (float*)0, n, 0);
  // layer 2
  k_gemm<<<gemmBlocks, 256, 0, stream>>>(xcur, bp + 32768, xlb, xrb, nstrips, n);
  k_agg<<<aggBlocks, 256, 0, stream>>>(off, csr, xlb, xrb, att2, b2, xcur,
                                       lng + 256, lnb + 256, xcur, (float*)0, n, 0);
  // layer 3 (single head, wide reduce; f32 output to d_out)
  k_gemm<<<gemmBlocks, 256, 0, stream>>>(xcur, bp + 65536, xlb, xrb, nstrips, n);
  k_agg<<<aggBlocks, 256, 0, stream>>>(off, csr, xlb, xrb, att3, b3, xcur,
                                       lng + 384, lnb + 384, (unsigned*)0, (float*)d_out, n, 1);
}